// Round 9
// baseline (58.078 us; speedup 1.0000x reference)
//
#include <hip/hip_runtime.h>

#define NN 1026   // nodes
#define NA 1024   // angles
#define BLK 1024
typedef float v2f __attribute__((ext_vector_type(2)));

__device__ __forceinline__ v2f vbc(float s) { return (v2f){s, s}; }

// minimax atan2, max err ~2e-6 rad; inputs never both zero here
__device__ __forceinline__ float fast_atan2f(float y, float x) {
    float ax = __builtin_fabsf(x), ay = __builtin_fabsf(y);
    float mx = fmaxf(ax, ay), mn = fminf(ax, ay);
    float a  = mn * __builtin_amdgcn_rcpf(mx);
    float s  = a * a;
    float r  = fmaf(s, -0.0117212f,  0.05265332f);
    r = fmaf(s, r, -0.11643287f);
    r = fmaf(s, r,  0.19354346f);
    r = fmaf(s, r, -0.33262347f);
    r = fmaf(s, r,  0.99997726f);
    r *= a;
    if (ay > ax)  r = 1.57079637f - r;
    if (x < 0.0f) r = 3.14159274f - r;
    return copysignf(r, y);
}

// bounded spin on an LDS flag (fail-visible, never hangs)
__device__ __forceinline__ void waitFlag(volatile int* f, int target) {
    int iters = 0;
    while (*f < target) {
        __builtin_amdgcn_s_sleep(1);
        if (++iters > (1 << 22)) break;
    }
    __asm__ __volatile__("" ::: "memory");   // fence: no LDS reads hoisted above
}

__global__ __launch_bounds__(BLK)
void equil_kernel(const float* __restrict__ pos0,
                  const float* __restrict__ tip_pos,
                  const float* __restrict__ thetas_ss,
                  const int*   __restrict__ buckle,
                  const float* __restrict__ kstiff_p,
                  const float* __restrict__ ksoft_p,
                  const float* __restrict__ kstretch_p,
                  float* __restrict__ out)
{
    __shared__ v2f pos[NN];      // node positions
    __shared__ v2f Ps[NA + 1];   // P_j = S_j + a_j ; slot 1024 = S_1024
    __shared__ v2f Qs[NA];       // Q_j = P_j - B_j
    __shared__ int aFlag[17];    // aFlag[w]=s: wave w finished phase AB of step s
    __shared__ int pFlag[16];    // pFlag[w]=s: wave w finished phase C  of step s

    const int b = blockIdx.x;
    const int t = threadIdx.x;
    const int w = t >> 6, l = t & 63;
    const float k_str  = kstretch_p[0];
    const float k_sd   = kstiff_p[0] - ksoft_p[0];
    const float k4soft = 4.0f * ksoft_p[0];

    // ---- init: thread t computes angle t, owns node t+2 (free for t<=1022) ----
    const v2f* p0g = (const v2f*)(pos0 + (size_t)b * 2052);
    v2f myp;
    if (t < 1023) myp = p0g[t + 2];
    else          myp = (v2f){tip_pos[2*b], tip_pos[2*b+1]};
    pos[t + 2] = myp;
    if (t < 2) pos[t] = p0g[t];      // fixed nodes 0,1 (never rewritten)
    if (t < 17) aFlag[t] = (t == 16) ? 1000 : 0;   // sentinel: wave15's right dep
    if (t < 16) pFlag[t] = 0;                       // "step 0 C done" = init pos

    const float TH = thetas_ss[t];
    const int4 bk  = ((const int4*)buckle)[t];
    const float npl = (float)(bk.x + bk.y + bk.z + bk.w);   // #(pm==+1)
    v2f vel = vbc(0.f);
    __syncthreads();   // one block-wide barrier: init visible everywhere

    for (int s = 1; s <= 64; ++s) {
        // wait: left neighbor's pos update of step s-1 (lanes 0,1 consume it)
        if (w > 0) waitFlag(&pFlag[w - 1], s - 1);

        // ---- phase AB: angle t from pos[t], pos[t+1], own myp ----
        v2f pa = pos[t], pb = pos[t + 1];
        v2f v1 = pb - pa;
        v2f v2 = myp - pb;
        float l2a = fmaf(v1.x, v1.x, v1.y * v1.y);
        float l2b = fmaf(v2.x, v2.x, v2.y * v2.y);
        float cr  = v1.x * v2.y - v1.y * v2.x;
        float dt_ = fmaf(v1.x, v2.x, v1.y * v2.y);
        float theta = fast_atan2f(cr, dt_);
        float cnt = (theta <  TH ? npl        : 0.f)
                  + (theta > -TH ? 4.f - npl  : 0.f);
        float K = fmaf(cnt, k_sd, k4soft);
        float m = K * (theta - TH);
        float ila = __builtin_amdgcn_rsqf(l2a);
        float ilb = __builtin_amdgcn_rsqf(l2b);
        float m1 = m * ila * ila;                 // m / l2a
        float m2 = m * ilb * ilb;                 // m / l2b
        v2f rot1 = (v2f){ v1.y, -v1.x};
        v2f rot2 = (v2f){ v2.y, -v2.x};
        v2f Bv = vbc(-m2) * rot2;                 // b_t (register)
        float sca = k_str * (1.0f - ila);
        v2f P  = vbc(sca) * v1 + vbc(m1) * rot1;  // S_t + a_t
        v2f Q  = P - Bv;
        Ps[t] = P;
        Qs[t] = Q;
        if (t == NA - 1) {   // slot 1024: S_1024 (stretch-only edge)
            float scb = k_str * (1.0f - ilb);
            Ps[NA] = vbc(scb) * v2;
        }
        __asm__ __volatile__("s_waitcnt lgkmcnt(0)" ::: "memory");
        if (l == 0) *(volatile int*)&aFlag[w] = s;

        // wait: right neighbor's P/Q of step s (lanes 62,63 consume it);
        // this also protects left neighbor's WAR on pos (it won't run C(s)
        // and overwrite our pos inputs until WE set aFlag above).
        waitFlag(&aFlag[w + 1], s);

        // ---- phase C: f(node t+2) = P[t+2] - Q[t+1] - B[t] ----
        if (t < 1023) {
            v2f Pn = Ps[t + 2];
            v2f Qm = Qs[t + 1];
            v2f f  = (Pn - Qm) - Bv;
            vel = vel + vbc(0.001f) * (f - vbc(2.0f) * vel);
            myp = myp + vbc(0.001f) * vel;
            pos[t + 2] = myp;
        }
        __asm__ __volatile__("s_waitcnt lgkmcnt(0)" ::: "memory");
        if (l == 0) *(volatile int*)&pFlag[w] = s;
    }

    // ---- epilogue: all outputs from registers/fixed LDS ----
    v2f* o = (v2f*)(out + (size_t)b * 2052);
    o[t + 2] = myp;            // t=1023 writes node 1025 = tip
    if (t < 2) o[t] = pos[t];
}

extern "C" void kernel_launch(void* const* d_in, const int* in_sizes, int n_in,
                              void* d_out, int out_size, void* d_ws, size_t ws_size,
                              hipStream_t stream) {
    const float* pos0   = (const float*)d_in[0];
    const float* tip    = (const float*)d_in[1];
    const float* thetas = (const float*)d_in[2];
    const int*   buckle = (const int*)  d_in[3];
    const float* ks     = (const float*)d_in[4];
    const float* ko     = (const float*)d_in[5];
    const float* kr     = (const float*)d_in[6];
    float* out = (float*)d_out;
    hipLaunchKernelGGL(equil_kernel, dim3(256), dim3(BLK), 0, stream,
                       pos0, tip, thetas, buckle, ks, ko, kr, out);
}

// Round 10
// 54.204 us; speedup vs baseline: 1.0715x; 1.0715x over previous
//
#include <hip/hip_runtime.h>

#define BLK 256
typedef float v2f __attribute__((ext_vector_type(2)));

__device__ __forceinline__ v2f vbc(float s) { return (v2f){s, s}; }

// minimax atan2, max err ~2e-6 rad; inputs never both zero here
__device__ __forceinline__ float fast_atan2f(float y, float x) {
    float ax = __builtin_fabsf(x), ay = __builtin_fabsf(y);
    float mx = fmaxf(ax, ay), mn = fminf(ax, ay);
    float a  = mn * __builtin_amdgcn_rcpf(mx);
    float s  = a * a;
    float r  = fmaf(s, -0.0117212f,  0.05265332f);
    r = fmaf(s, r, -0.11643287f);
    r = fmaf(s, r,  0.19354346f);
    r = fmaf(s, r, -0.33262347f);
    r = fmaf(s, r,  0.99997726f);
    r *= a;
    if (ay > ax)  r = 1.57079637f - r;
    if (x < 0.0f) r = 3.14159274f - r;
    return copysignf(r, y);
}

__global__ __launch_bounds__(BLK)
void equil_kernel(const float* __restrict__ pos0,
                  const float* __restrict__ tip_pos,
                  const float* __restrict__ thetas_ss,
                  const int*   __restrict__ buckle,
                  const float* __restrict__ kstiff_p,
                  const float* __restrict__ ksoft_p,
                  const float* __restrict__ kstretch_p,
                  float* __restrict__ out)
{
    // double-buffered position mirror: slots 0..1025 = nodes, 1026..1027 = safe pads
    __shared__ v2f buf[2][1028];

    const int b  = blockIdx.x;
    const int t  = threadIdx.x;
    const int n0 = 2 + 4 * t;            // first owned node (2..1022)
    const float k_str  = kstretch_p[0];
    const float k_sd   = kstiff_p[0] - ksoft_p[0];
    const float k4soft = 4.0f * ksoft_p[0];

    // ---- init: own 4 nodes ----
    const v2f* p0g = (const v2f*)(pos0 + (size_t)b * 2052);
    v2f xx[4];
    #pragma unroll
    for (int k = 0; k < 4; ++k) xx[k] = p0g[n0 + k];
    if (t == BLK - 1) xx[3] = (v2f){tip_pos[2*b], tip_pos[2*b+1]};   // node 1025 = tip

    #pragma unroll
    for (int k = 0; k < 4; ++k) { buf[0][n0 + k] = xx[k]; buf[1][n0 + k] = xx[k]; }
    if (t == 0) {
        v2f c0 = p0g[0], c1 = p0g[1];
        buf[0][0] = c0;  buf[1][0] = c0;     // fixed nodes, never rewritten
        buf[0][1] = c1;  buf[1][1] = c1;
        buf[0][1026] = (v2f){1.f, 0.f};  buf[1][1026] = (v2f){1.f, 0.f};   // pads
        buf[0][1027] = (v2f){2.f, 0.f};  buf[1][1027] = (v2f){2.f, 0.f};
    }

    // per-lane constants: angles j = 4t+q, q=0..5 (2 left halo, 4 own-ish, clamped)
    float TH[6], NPL[6], MSK[6];
    #pragma unroll
    for (int q = 0; q < 6; ++q) {
        int j  = 4 * t + q;
        int jc = j < 1023 ? j : 1023;
        TH[q]  = thetas_ss[jc];
        int4 bb = ((const int4*)buckle)[jc];
        NPL[q] = (float)(bb.x + bb.y + bb.z + bb.w);
        MSK[q] = (j < 1024) ? 1.f : 0.f;     // angle exists?
    }
    float UM[4];
    #pragma unroll
    for (int k = 0; k < 4; ++k) UM[k] = (n0 + k <= 1024) ? 1.f : 0.f;  // free node?

    v2f vv[4];
    #pragma unroll
    for (int k = 0; k < 4; ++k) vv[k] = vbc(0.f);

    __syncthreads();

    int cur = 0;
    for (int s = 0; s < 64; ++s) {
        const v2f* bc = buf[cur];
        // X[0..7] = nodes n0-2 .. n0+5 (halos from LDS, own from regs)
        v2f X[8];
        X[0] = bc[n0 - 2];  X[1] = bc[n0 - 1];
        X[2] = xx[0]; X[3] = xx[1]; X[4] = xx[2]; X[5] = xx[3];
        X[6] = bc[n0 + 4];  X[7] = bc[n0 + 5];

        // edges e[i] = edge (n0-2+i), i=0..6
        v2f e[7]; float il[7], il2[7];
        #pragma unroll
        for (int i = 0; i < 7; ++i) {
            e[i] = X[i + 1] - X[i];
            float l2 = fmaf(e[i].x, e[i].x, e[i].y * e[i].y);
            il[i]  = __builtin_amdgcn_rsqf(l2);
            il2[i] = il[i] * il[i];
        }

        // angle moments m[q], angle j=4t+q uses edges q,q+1  (masked past end)
        float mm[6];
        #pragma unroll
        for (int q = 0; q < 6; ++q) {
            float cr  = e[q].x * e[q+1].y - e[q].y * e[q+1].x;
            float dt_ = fmaf(e[q].x, e[q+1].x, e[q].y * e[q+1].y);
            float th  = fast_atan2f(cr, dt_);
            float cnt = (th <  TH[q] ? NPL[q]       : 0.f)
                      + (th > -TH[q] ? 4.f - NPL[q] : 0.f);
            float K = fmaf(cnt, k_sd, k4soft);
            mm[q] = MSK[q] * (K * (th - TH[q]));
        }

        // P[q] = S_q + a_q (q=1..5), B[q] = b_q (q=0..4), Q = P - B (q=1..4)
        v2f Pp[6], Bb[5], Qq[5];
        #pragma unroll
        for (int q = 1; q < 6; ++q) {
            float sc = k_str * (1.0f - il[q]);
            float m1 = mm[q] * il2[q];
            Pp[q] = vbc(sc) * e[q] + vbc(m1) * (v2f){e[q].y, -e[q].x};
        }
        #pragma unroll
        for (int q = 0; q < 5; ++q) {
            float m2 = mm[q] * il2[q + 1];
            Bb[q] = (v2f){ -m2 * e[q+1].y, m2 * e[q+1].x };
        }
        #pragma unroll
        for (int q = 1; q < 5; ++q) Qq[q] = Pp[q] - Bb[q];

        // f(node n0+k) = P[k+2] - Q[k+1] - B[k]; integrate
        #pragma unroll
        for (int k = 0; k < 4; ++k) {
            v2f f = (Pp[k+2] - Qq[k+1] - Bb[k]) * vbc(UM[k]);
            vv[k] = vv[k] + vbc(0.001f) * (f - vbc(2.0f) * vv[k]);
            xx[k] = xx[k] + vbc(0.001f) * vv[k];
        }

        // publish own nodes for next step
        v2f* bn = buf[cur ^ 1];
        #pragma unroll
        for (int k = 0; k < 4; ++k) bn[n0 + k] = xx[k];
        __syncthreads();
        cur ^= 1;
    }

    // ---- epilogue ----
    v2f* o = (v2f*)(out + (size_t)b * 2052);
    #pragma unroll
    for (int k = 0; k < 4; ++k) o[n0 + k] = xx[k];
    if (t == 0) { o[0] = buf[0][0]; o[1] = buf[0][1]; }
}

extern "C" void kernel_launch(void* const* d_in, const int* in_sizes, int n_in,
                              void* d_out, int out_size, void* d_ws, size_t ws_size,
                              hipStream_t stream) {
    const float* pos0   = (const float*)d_in[0];
    const float* tip    = (const float*)d_in[1];
    const float* thetas = (const float*)d_in[2];
    const int*   buckle = (const int*)  d_in[3];
    const float* ks     = (const float*)d_in[4];
    const float* ko     = (const float*)d_in[5];
    const float* kr     = (const float*)d_in[6];
    float* out = (float*)d_out;
    hipLaunchKernelGGL(equil_kernel, dim3(256), dim3(BLK), 0, stream,
                       pos0, tip, thetas, buckle, ks, ko, kr, out);
}